// Round 6
// baseline (7887.263 us; speedup 1.0000x reference)
//
#include <hip/hip_runtime.h>

// Equivariant graph attention — fp32. R6 = R5 split kernels + latency fixes:
//  - __launch_bounds__(256,3): cap ~170 VGPR -> 3 waves/SIMD (R5 hit the 256
//    cap -> 2 waves/SIMD, occupancy 11%, VALUBusy 16%, latency-bound)
//  - software pipeline: prefetch next batch's eid at top, next xattr mid
//    layer-2 FMA stream, epilogue operands before layer-2 -> hide the
//    csr->xattr 2-level gather (~900 cyc) under compute
//  - grid 768 blocks = 3072 waves = exactly resident at 3 waves/SIMD

constexpr float INV3    = 0.57735026918962576f;  // 1/sqrt(3)
constexpr float INV_SQ8 = 0.35355339059327373f;  // 1/sqrt(8)   folded into w1 regs
constexpr float INV_HID = 0.125f;                // 1/sqrt(64)  folded into LDS w2
constexpr float INV_FAN = 0.015625f;             // 1/sqrt(4*32*32)
constexpr float INV_L   = 0.125f;                // 1/sqrt(64)
#define GR_BLOCKS 768

__device__ __forceinline__ float gelu_tanh(float x) {
  float u = 0.7978845608028654f * (x + 0.044715f * x * x * x);
  float e = __expf(2.0f * u);
  return x * (1.0f - 1.0f / (e + 1.0f));
}

// ---------------- CSR build ----------------
__global__ void k_zero(int* __restrict__ p, int n) {
  int i = blockIdx.x * 256 + threadIdx.x;
  if (i < n) p[i] = 0;
}

__global__ void k_hist(const int* __restrict__ dst, int* __restrict__ cnt, int E) {
  int e = blockIdx.x * 256 + threadIdx.x;
  if (e < E) atomicAdd(&cnt[dst[e]], 1);
}

__global__ __launch_bounds__(256) void k_scan(const int* __restrict__ cnt,
                                              int* __restrict__ rowptr, int N) {
  __shared__ int wsum[4];
  __shared__ int woff[4];
  __shared__ int carry;
  int t = threadIdx.x, wave = t >> 6, lane = t & 63;
  if (t == 0) { carry = 0; rowptr[0] = 0; }
  __syncthreads();
  for (int base = 0; base < N; base += 1024) {
    int i0 = base + t * 4;
    int c0 = (i0     < N) ? cnt[i0]     : 0;
    int c1 = (i0 + 1 < N) ? cnt[i0 + 1] : 0;
    int c2 = (i0 + 2 < N) ? cnt[i0 + 2] : 0;
    int c3 = (i0 + 3 < N) ? cnt[i0 + 3] : 0;
    int s0 = c0, s1 = s0 + c1, s2 = s1 + c2, s3 = s2 + c3;
    int inc = s3;
#pragma unroll
    for (int off = 1; off < 64; off <<= 1) {
      int y = __shfl_up(inc, off, 64);
      if (lane >= off) inc += y;
    }
    if (lane == 63) wsum[wave] = inc;
    __syncthreads();
    if (t == 0) {
      int r = 0;
      for (int w = 0; w < 4; w++) { woff[w] = r; r += wsum[w]; }
    }
    __syncthreads();
    int excl = inc - s3 + woff[wave] + carry;
    if (i0     < N) rowptr[i0 + 1] = excl + s0;
    if (i0 + 1 < N) rowptr[i0 + 2] = excl + s1;
    if (i0 + 2 < N) rowptr[i0 + 3] = excl + s2;
    if (i0 + 3 < N) rowptr[i0 + 4] = excl + s3;
    __syncthreads();
    if (t == 255) carry = excl + s3;
    __syncthreads();
  }
}

__global__ void k_fill(const int* __restrict__ dst, const int* __restrict__ rowptr,
                       int* __restrict__ cursor, int* __restrict__ csr, int E) {
  int e = blockIdx.x * 256 + threadIdx.x;
  if (e < E) {
    int d = dst[e];
    int s = atomicAdd(&cursor[d], 1);
    csr[rowptr[d] + s] = e;
  }
}

// ---------------- per-node A precompute ----------------
// Lane-owned layout: A[n][lane2][r], lane2=0..63, r=0..15.
//   lane2 = v    : r0..3 = A0[h=r][v]; r=4+3h+d = A2[h][v][d]
//   lane2 = 32+v : r0..3 = A1[h=r][v]; r=4+3h+d = A3[h][v][d]
__global__ __launch_bounds__(256) void k_nodeA(const float* __restrict__ node_f,
                                               const float* __restrict__ Wdot,
                                               float* __restrict__ A, int N) {
  __shared__ float Wd[16384];
  __shared__ float nfs[32 * 128];
  int t = threadIdx.x;
  for (int i = t; i < 16384; i += 256) Wd[i] = Wdot[i];
  int n0 = blockIdx.x * 32;
  int nEnd = min(32, N - n0);
  for (int i = t; i < nEnd * 128; i += 256) nfs[i] = node_f[n0 * 128 + i];
  __syncthreads();
  for (int nn = 0; nn < nEnd; ++nn) {
    const float* nf = &nfs[nn * 128];
    float* An = &A[(size_t)(n0 + nn) * 1024];
#pragma unroll
    for (int k = 0; k < 4; k++) {
      int o = t + k * 256;          // o = lane2*16 + r
      int lane2 = o >> 4, r = o & 15;
      int v = lane2 & 31;
      bool hi2 = lane2 >= 32;
      float acc = 0.f;
      if (r < 4) {
        const float* W = &Wd[(hi2 ? 4096 : 0) + r * 1024 + v];
#pragma unroll
        for (int u = 0; u < 32; u++) acc += W[u * 32] * nf[u];
      } else {
        int rr = r - 4;
        int h = rr / 3, d = rr - 3 * h;
        const float* W = &Wd[(hi2 ? 3 * 4096 : 2 * 4096) + h * 1024 + v];
#pragma unroll
        for (int u = 0; u < 32; u++) acc += W[u * 32] * nf[32 + 3 * u + d];
      }
      An[o] = acc;
    }
  }
}

// ---------------- pass 1: k-MLP + logits -> expw ----------------
__global__ __launch_bounds__(256, 3) void k_edge1(
    const int* __restrict__ csr, const int* __restrict__ rowptr,
    const int* __restrict__ esrc,
    const float* __restrict__ xattr, const float* __restrict__ eattr,
    const float* __restrict__ cutoff, const float* __restrict__ node_f,
    const float* __restrict__ wk1, const float* __restrict__ bk1,
    const float* __restrict__ wk2,
    const float* __restrict__ A,
    float* __restrict__ expw, int N)
{
  __shared__ __align__(16) float4 w2k[16 * 128];  // 32 KiB, [q][j].[l%4], *INV_HID
  __shared__ __align__(16) float  hsb[4][256];    //  4 KiB, per-wave h buffer

  int t = threadIdx.x, wave = t >> 6, lane = t & 63;
  for (int idx = t; idx < 8192; idx += 256) {
    int l = idx >> 7, j = idx & 127;
    ((float*)&w2k[(l >> 2) * 128 + j])[l & 3] = wk2[idx] * INV_HID;
  }
  float w1r[8];
#pragma unroll
  for (int r = 0; r < 8; r++) w1r[r] = wk1[r * 64 + lane] * INV_SQ8;
  float b1r = bk1[lane];
  __syncthreads();   // only barrier

  int v = lane & 31;
  bool hi_ = lane >= 32;
  float* hs = hsb[wave];
  const float4* xattr4 = (const float4*)xattr;
  const float4* eattr4 = (const float4*)eattr;

  for (int n = blockIdx.x * 4 + wave; n < N; n += GR_BLOCKS * 4) {
    float Ar[16];
    {
      const float4* Ap = (const float4*)(A + (size_t)n * 1024 + lane * 16);
      float4 q0 = Ap[0], q1 = Ap[1], q2 = Ap[2], q3 = Ap[3];
      Ar[0] = q0.x;  Ar[1] = q0.y;  Ar[2] = q0.z;  Ar[3] = q0.w;
      Ar[4] = q1.x;  Ar[5] = q1.y;  Ar[6] = q1.z;  Ar[7] = q1.w;
      Ar[8] = q2.x;  Ar[9] = q2.y;  Ar[10] = q2.z; Ar[11] = q2.w;
      Ar[12] = q3.x; Ar[13] = q3.y; Ar[14] = q3.z; Ar[15] = q3.w;
    }
    int row0 = rowptr[n];
    int deg  = rowptr[n + 1] - row0;
    if (deg <= 0) continue;

    // prologue: batch 0 eid + xattr
    int eidc[4]; float4 xac[4], xbc[4];
#pragma unroll
    for (int k = 0; k < 4; k++) eidc[k] = csr[row0 + min(k, deg - 1)];
#pragma unroll
    for (int k = 0; k < 4; k++) {
      xac[k] = xattr4[(size_t)eidc[k] * 2];
      xbc[k] = xattr4[(size_t)eidc[k] * 2 + 1];
    }

    for (int sb = 0; sb < deg; sb += 4) {
      // prefetch next batch's eid (needed ~2000 cyc from now)
      int nb = (sb + 4 < deg) ? sb + 4 : sb;
      int eidn[4];
#pragma unroll
      for (int k = 0; k < 4; k++) eidn[k] = csr[row0 + min(nb + k, deg - 1)];
      // layer 1 on current batch (operands resident)
#pragma unroll
      for (int k = 0; k < 4; k++) {
        float ak = xac[k].x * w1r[0] + xac[k].y * w1r[1] + xac[k].z * w1r[2] + xac[k].w * w1r[3]
                 + xbc[k].x * w1r[4] + xbc[k].y * w1r[5] + xbc[k].z * w1r[6] + xbc[k].w * w1r[7];
        hs[k * 64 + lane] = gelu_tanh(ak + b1r);
      }
      // epilogue operand prefetch for current batch (needed after layer 2)
      float4 ya[4]; float cut[4], nf0[4], nf1[4], nf2[4];
#pragma unroll
      for (int k = 0; k < 4; k++) {
        int e = eidc[k];
        ya[k] = eattr4[e]; cut[k] = cutoff[e];
        const float* nf = node_f + (size_t)esrc[e] * 128;
        nf0[k] = nf[hi_ ? 32 + 3 * v : v];
        nf1[k] = nf[hi_ ? 33 + 3 * v : v];
        nf2[k] = nf[hi_ ? 34 + 3 * v : v];
      }
      // layer 2, first half
      float a0[4] = {0, 0, 0, 0}, a1[4] = {0, 0, 0, 0};
#pragma unroll
      for (int q = 0; q < 8; ++q) {
        float4 wA = w2k[q * 128 + lane];
        float4 wB = w2k[q * 128 + 64 + lane];
#pragma unroll
        for (int k = 0; k < 4; k++) {
          float4 hq = *(const float4*)&hs[k * 64 + q * 4];
          a0[k] += hq.x * wA.x + hq.y * wA.y + hq.z * wA.z + hq.w * wA.w;
          a1[k] += hq.x * wB.x + hq.y * wB.y + hq.z * wB.z + hq.w * wB.w;
        }
      }
      // prefetch next batch's xattr (eidn has arrived by now; result needed
      // next iteration -> latency hides under remaining q-loop + epilogue)
      float4 xan[4], xbn[4];
#pragma unroll
      for (int k = 0; k < 4; k++) {
        xan[k] = xattr4[(size_t)eidn[k] * 2];
        xbn[k] = xattr4[(size_t)eidn[k] * 2 + 1];
      }
      // layer 2, second half
#pragma unroll
      for (int q = 8; q < 16; ++q) {
        float4 wA = w2k[q * 128 + lane];
        float4 wB = w2k[q * 128 + 64 + lane];
#pragma unroll
        for (int k = 0; k < 4; k++) {
          float4 hq = *(const float4*)&hs[k * 64 + q * 4];
          a0[k] += hq.x * wA.x + hq.y * wA.y + hq.z * wA.z + hq.w * wA.w;
          a1[k] += hq.x * wB.x + hq.y * wB.y + hq.z * wB.z + hq.w * wB.w;
        }
      }
      // per-edge epilogue: logit -> expw
#pragma unroll
      for (int k = 0; k < 4; k++) {
        int s = sb + k;
        float dotv = nf0[k] * ya[k].y + nf1[k] * ya[k].z + nf2[k] * ya[k].w;
        float kscal = hi_ ? (a0[k] * dotv * INV3) : (a0[k] * nf0[k] * ya[k].x);
        float cf = INV3 * a1[k] * (hi_ ? ya[k].x : nf0[k]);
        float m0 = hi_ ? nf0[k] : ya[k].y, m1 = hi_ ? nf1[k] : ya[k].z, m2 = hi_ ? nf2[k] : ya[k].w;
        float p0 = Ar[0] * kscal + cf * (Ar[4]  * m0 + Ar[5]  * m1 + Ar[6]  * m2);
        float p1 = Ar[1] * kscal + cf * (Ar[7]  * m0 + Ar[8]  * m1 + Ar[9]  * m2);
        float p2 = Ar[2] * kscal + cf * (Ar[10] * m0 + Ar[11] * m1 + Ar[12] * m2);
        float p3 = Ar[3] * kscal + cf * (Ar[13] * m0 + Ar[14] * m1 + Ar[15] * m2);
#pragma unroll
        for (int off = 32; off; off >>= 1) {
          p0 += __shfl_xor(p0, off, 64);
          p1 += __shfl_xor(p1, off, 64);
          p2 += __shfl_xor(p2, off, 64);
          p3 += __shfl_xor(p3, off, 64);
        }
        float ph = (lane & 2) ? ((lane & 1) ? p3 : p2) : ((lane & 1) ? p1 : p0);
        if (lane < 4 && s < deg)
          expw[(size_t)(row0 + s) * 4 + lane] = cut[k] * __expf(ph * INV_FAN);
      }
      // rotate pipeline registers
#pragma unroll
      for (int k = 0; k < 4; k++) { eidc[k] = eidn[k]; xac[k] = xan[k]; xbc[k] = xbn[k]; }
    }
  }
}

// ---------------- pass 2: z, v-MLP, aggregation, output linear ----------------
__global__ __launch_bounds__(256, 3) void k_edge2(
    const int* __restrict__ csr, const int* __restrict__ rowptr,
    const int* __restrict__ esrc,
    const float* __restrict__ xattr, const float* __restrict__ eattr,
    const float* __restrict__ node_f,
    const float* __restrict__ wv1, const float* __restrict__ bv1,
    const float* __restrict__ wv2,
    const float* __restrict__ Wls, const float* __restrict__ Wlv,
    const float* __restrict__ expw,
    float* __restrict__ out, int N)
{
  __shared__ __align__(16) float4 w2v[16 * 128];  // 32 KiB
  __shared__ __align__(16) float  hsb[4][256];    //  4 KiB

  int t = threadIdx.x, wave = t >> 6, lane = t & 63;
  for (int idx = t; idx < 8192; idx += 256) {
    int l = idx >> 7, j = idx & 127;
    ((float*)&w2v[(l >> 2) * 128 + j])[l & 3] = wv2[idx] * INV_HID;
  }
  float w1r[8];
#pragma unroll
  for (int r = 0; r < 8; r++) w1r[r] = wv1[r * 64 + lane] * INV_SQ8;
  float b1r = bv1[lane];
  __syncthreads();   // only barrier

  int v = lane & 31;
  bool hi_ = lane >= 32;
  int hh = v >> 3;
  float* hs = hsb[wave];
  const float4* xattr4 = (const float4*)xattr;
  const float4* eattr4 = (const float4*)eattr;

  for (int n = blockIdx.x * 4 + wave; n < N; n += GR_BLOCKS * 4) {
    int row0 = rowptr[n];
    int deg  = rowptr[n + 1] - row0;

    // z per head (lane hz=lane&3 sums head hz over slots lane>>2 stride 16)
    float pz = 0.f;
    {
      int hz = lane & 3;
      for (int s = lane >> 2; s < deg; s += 16)
        pz += expw[(size_t)(row0 + s) * 4 + hz];
#pragma unroll
      for (int off = 4; off < 64; off <<= 1) pz += __shfl_xor(pz, off, 64);
    }
    float zf = __shfl(pz, hh, 64);
    float rz = rsqrtf(zf == 0.f ? 1.f : zf);

    float accS = 0.f, ac0 = 0.f, ac1 = 0.f, ac2 = 0.f;
    if (deg > 0) {
      int eidc[4]; float4 xac[4], xbc[4];
#pragma unroll
      for (int k = 0; k < 4; k++) eidc[k] = csr[row0 + min(k, deg - 1)];
#pragma unroll
      for (int k = 0; k < 4; k++) {
        xac[k] = xattr4[(size_t)eidc[k] * 2];
        xbc[k] = xattr4[(size_t)eidc[k] * 2 + 1];
      }
      for (int sb = 0; sb < deg; sb += 4) {
        int nb = (sb + 4 < deg) ? sb + 4 : sb;
        int eidn[4];
#pragma unroll
        for (int k = 0; k < 4; k++) eidn[k] = csr[row0 + min(nb + k, deg - 1)];
        // layer 1
#pragma unroll
        for (int k = 0; k < 4; k++) {
          float av = xac[k].x * w1r[0] + xac[k].y * w1r[1] + xac[k].z * w1r[2] + xac[k].w * w1r[3]
                   + xbc[k].x * w1r[4] + xbc[k].y * w1r[5] + xbc[k].z * w1r[6] + xbc[k].w * w1r[7];
          hs[k * 64 + lane] = gelu_tanh(av + b1r);
        }
        // epilogue operand prefetch (current batch)
        float4 ya[4]; float ewc[4], nf0[4], nf1[4], nf2[4];
#pragma unroll
        for (int k = 0; k < 4; k++) {
          int e = eidc[k];
          ya[k] = eattr4[e];
          ewc[k] = expw[(size_t)(row0 + min(sb + k, deg - 1)) * 4 + hh];
          const float* nf = node_f + (size_t)esrc[e] * 128;
          nf0[k] = nf[hi_ ? 32 + 3 * v : v];
          nf1[k] = nf[hi_ ? 33 + 3 * v : v];
          nf2[k] = nf[hi_ ? 34 + 3 * v : v];
        }
        float a0[4] = {0, 0, 0, 0}, a1[4] = {0, 0, 0, 0};
#pragma unroll
        for (int q = 0; q < 8; ++q) {
          float4 wA = w2v[q * 128 + lane];
          float4 wB = w2v[q * 128 + 64 + lane];
#pragma unroll
          for (int k = 0; k < 4; k++) {
            float4 hq = *(const float4*)&hs[k * 64 + q * 4];
            a0[k] += hq.x * wA.x + hq.y * wA.y + hq.z * wA.z + hq.w * wA.w;
            a1[k] += hq.x * wB.x + hq.y * wB.y + hq.z * wB.z + hq.w * wB.w;
          }
        }
        float4 xan[4], xbn[4];
#pragma unroll
        for (int k = 0; k < 4; k++) {
          xan[k] = xattr4[(size_t)eidn[k] * 2];
          xbn[k] = xattr4[(size_t)eidn[k] * 2 + 1];
        }
#pragma unroll
        for (int q = 8; q < 16; ++q) {
          float4 wA = w2v[q * 128 + lane];
          float4 wB = w2v[q * 128 + 64 + lane];
#pragma unroll
          for (int k = 0; k < 4; k++) {
            float4 hq = *(const float4*)&hs[k * 64 + q * 4];
            a0[k] += hq.x * wA.x + hq.y * wA.y + hq.z * wA.z + hq.w * wA.w;
            a1[k] += hq.x * wB.x + hq.y * wB.y + hq.z * wB.z + hq.w * wB.w;
          }
        }
        // per-edge epilogue: sqrt(expw)*v accumulate
#pragma unroll
        for (int k = 0; k < 4; k++) {
          int s = sb + k;
          float ew = (s < deg) ? ewc[k] : 0.f;
          float sq = sqrtf(ew);     // sa = sqrt(ew)*rsqrt(z); rz applied at end
          float dotv = nf0[k] * ya[k].y + nf1[k] * ya[k].z + nf2[k] * ya[k].w;
          float sterm = hi_ ? dotv * INV3 : nf0[k] * ya[k].x;
          accS += a0[k] * sterm * sq;
          float coef = a1[k] * sq * (hi_ ? ya[k].x : nf0[k]);
          float m0 = hi_ ? nf0[k] : ya[k].y, m1 = hi_ ? nf1[k] : ya[k].z, m2 = hi_ ? nf2[k] : ya[k].w;
          ac0 += coef * m0; ac1 += coef * m1; ac2 += coef * m2;
        }
        // rotate
#pragma unroll
        for (int k = 0; k < 4; k++) { eidc[k] = eidn[k]; xac[k] = xan[k]; xbc[k] = xbn[k]; }
      }
    }
    accS *= rz; ac0 *= rz; ac1 *= rz; ac2 *= rz;

    // stage agg channels (wave-local), fused output linear
    {
      int chS = hi_ ? 32 + v : v;
      int chV = (hi_ ? 160 : 64) + 3 * v;
      hs[chS] = accS;
      hs[chV] = ac0; hs[chV + 1] = ac1; hs[chV + 2] = ac2;
    }
#pragma unroll
    for (int jj = 0; jj < 2; ++jj) {
      int j = 2 * lane + jj;
      float o = 0.f;
      if (j < 32) {
#pragma unroll
        for (int u = 0; u < 64; u++) o += hs[u] * Wls[u * 32 + j];
      } else {
        int i2 = j - 32, w2i = i2 / 3, d2 = i2 - 3 * w2i;
#pragma unroll
        for (int u = 0; u < 64; u++) o += hs[64 + u * 3 + d2] * Wlv[u * 32 + w2i];
      }
      out[(size_t)n * 128 + j] = o * INV_L;
    }
  }
}

// ---------------- host launcher ----------------
extern "C" void kernel_launch(void* const* d_in, const int* in_sizes, int n_in,
                              void* d_out, int out_size, void* d_ws, size_t ws_size,
                              hipStream_t stream) {
  const int*   esrc   = (const int*)d_in[0];
  const int*   edst   = (const int*)d_in[1];
  const float* xattr  = (const float*)d_in[2];
  const float* eattr  = (const float*)d_in[3];
  const float* cutoff = (const float*)d_in[4];
  const float* node_f = (const float*)d_in[5];
  const float* wk1    = (const float*)d_in[6];
  const float* bk1    = (const float*)d_in[7];
  const float* wk2    = (const float*)d_in[8];
  const float* wv1    = (const float*)d_in[9];
  const float* bv1    = (const float*)d_in[10];
  const float* wv2    = (const float*)d_in[11];
  const float* Wdot   = (const float*)d_in[12];
  const float* Wls    = (const float*)d_in[13];
  const float* Wlv    = (const float*)d_in[14];
  float* out = (float*)d_out;

  int E = in_sizes[0];
  int N = in_sizes[5] / 128;

  // workspace (~48 MB): A | expw | counts | cursor | rowptr | csr
  float* A     = (float*)d_ws;                  // N*1024 f32
  float* expw  = A + (size_t)N * 1024;          // E*4 f32
  int* counts  = (int*)(expw + (size_t)E * 4);  // N
  int* cursor  = counts + N;                    // N
  int* rowptr  = cursor + N;                    // N+1
  int* csr     = rowptr + (N + 1);              // E

  k_zero<<<(2 * N + 255) / 256, 256, 0, stream>>>(counts, 2 * N);
  k_hist<<<(E + 255) / 256, 256, 0, stream>>>(edst, counts, E);
  k_scan<<<1, 256, 0, stream>>>(counts, rowptr, N);
  k_fill<<<(E + 255) / 256, 256, 0, stream>>>(edst, rowptr, cursor, csr, E);
  k_nodeA<<<(N + 31) / 32, 256, 0, stream>>>(node_f, Wdot, A, N);
  k_edge1<<<GR_BLOCKS, 256, 0, stream>>>(csr, rowptr, esrc, xattr, eattr, cutoff,
                                         node_f, wk1, bk1, wk2, A, expw, N);
  k_edge2<<<GR_BLOCKS, 256, 0, stream>>>(csr, rowptr, esrc, xattr, eattr, node_f,
                                         wv1, bv1, wv2, Wls, Wlv, expw, out, N);
}